// Round 1
// baseline (24235.835 us; speedup 1.0000x reference)
//
#include <hip/hip_runtime.h>
#include <hip/hip_cooperative_groups.h>

typedef _Float16 f16;
typedef f16 f16x4 __attribute__((ext_vector_type(4)));
typedef f16 f16x8 __attribute__((ext_vector_type(8)));
typedef float f32x4 __attribute__((ext_vector_type(4)));

#define T_STEPS 512
#define B_SZ    64
#define NIN     1024
#define NH      2048

// workspace layout (bytes)
//   Z    f16 [512*64, 2048]  : 134,217,728  @ 0
//   hbuf f16 [2][64*2048]    :     524,288  @ 134,217,728
//   U16  f16 [2048,1024]     :   4,194,304  @ 134,742,016
//   W16  f16 [2048,2048]     :   8,388,608  @ 138,936,320
// total ~140.5 MB
#define WS_Z    0
#define WS_HBUF 134217728
#define WS_U16  134742016
#define WS_W16  138936320

__device__ __forceinline__ void gload16(const void* g, void* l) {
  __builtin_amdgcn_global_load_lds(
      (const __attribute__((address_space(1))) unsigned int*)g,
      (__attribute__((address_space(3))) unsigned int*)l, 16, 0, 0);
}

// ---------------- cast U_w, W_w -> f16 ----------------
__global__ void cast_uw_kernel(const float* __restrict__ U,
                               const float* __restrict__ W,
                               f16* __restrict__ Uo, f16* __restrict__ Wo) {
  const long NU = (long)NH * NIN;   // 2,097,152
  const long NW = (long)NH * NH;    // 4,194,304
  long total4 = (NU + NW) >> 2;
  for (long i = (long)blockIdx.x * blockDim.x + threadIdx.x; i < total4;
       i += (long)gridDim.x * blockDim.x) {
    long e = i << 2;
    const float* src; f16* dst;
    if (e < NU) { src = U + e; dst = Uo + e; }
    else        { src = W + (e - NU); dst = Wo + (e - NU); }
    float4 v = *(const float4*)src;
    f16x4 o = { (f16)v.x, (f16)v.y, (f16)v.z, (f16)v.w };
    *(f16x4*)dst = o;
  }
}

// ---------------- z GEMM: Z = x @ U16^T + U_b  (f16 out) ----------------
// M = T*B = 32768, N = 2048, K = 1024.  128x128 tile, BK=32, 4 waves.
__global__ __launch_bounds__(256) void zgemm_kernel(
    const float* __restrict__ X,   // [32768,1024] fp32
    const f16*   __restrict__ Bm,  // U16 [2048,1024]
    const float* __restrict__ bias,
    f16*         __restrict__ Z) {
  __shared__ f16 As[128 * 32];
  __shared__ f16 Bs[128 * 32];
  const int bm = blockIdx.x >> 4, bn = blockIdx.x & 15;
  const int tid = threadIdx.x, lane = tid & 63, w = tid >> 6;
  const int wr = w >> 1, wc = w & 1;
  const int fr = lane & 15, fq = lane >> 4;
  f32x4 acc[4][4] = {};
  const long rowA0 = (long)bm * 128;
  const int  rowB0 = bn * 128;
  const int r = tid >> 2, cblk = (tid & 3) * 8;

  for (int kk = 0; kk < 32; ++kk) {
    const int K0 = kk * 32;
    if (kk) __syncthreads();           // prev LDS reads done before overwrite
    // ---- A: fp32 -> f16 reg-staged (2 x 64 rows) ----
    {
      const float* g0 = X + (rowA0 + r) * NIN + K0 + cblk;
      float4 p = *(const float4*)g0;
      float4 q = *(const float4*)(g0 + 4);
      f16x8 v = { (f16)p.x,(f16)p.y,(f16)p.z,(f16)p.w,
                  (f16)q.x,(f16)q.y,(f16)q.z,(f16)q.w };
      *(f16x8*)((char*)As + tid * 16) = v;
      const float* g1 = g0 + 64 * NIN;
      float4 p1 = *(const float4*)g1;
      float4 q1 = *(const float4*)(g1 + 4);
      f16x8 v1 = { (f16)p1.x,(f16)p1.y,(f16)p1.z,(f16)p1.w,
                   (f16)q1.x,(f16)q1.y,(f16)q1.z,(f16)q1.w };
      *(f16x8*)((char*)As + 4096 + tid * 16) = v1;
    }
    // ---- B: f16 via global_load_lds (2 x 64 rows) ----
    gload16(Bm + (long)(rowB0 + r) * NIN + K0 + cblk, (char*)Bs + tid * 16);
    gload16(Bm + (long)(rowB0 + 64 + r) * NIN + K0 + cblk,
            (char*)Bs + 4096 + tid * 16);
    __syncthreads();                   // drains vmcnt + lgkmcnt

    f16x8 a[4], b[4];
#pragma unroll
    for (int m = 0; m < 4; ++m)
      a[m] = *(const f16x8*)((char*)As + ((wr * 64 + m * 16 + fr) * 32 + fq * 8) * 2);
#pragma unroll
    for (int n = 0; n < 4; ++n)
      b[n] = *(const f16x8*)((char*)Bs + ((wc * 64 + n * 16 + fr) * 32 + fq * 8) * 2);
#pragma unroll
    for (int m = 0; m < 4; ++m)
#pragma unroll
      for (int n = 0; n < 4; ++n)
        acc[m][n] = __builtin_amdgcn_mfma_f32_16x16x32_f16(a[m], b[n], acc[m][n], 0, 0, 0);
  }
  // epilogue: + bias, f16 store
#pragma unroll
  for (int n = 0; n < 4; ++n) {
    const int col = rowB0 + wc * 64 + n * 16 + fr;
    const float ub = bias[col];
#pragma unroll
    for (int m = 0; m < 4; ++m) {
      const long row = rowA0 + wr * 64 + m * 16 + fq * 4;
#pragma unroll
      for (int j = 0; j < 4; ++j)
        Z[(row + j) * NH + col] = (f16)(acc[m][n][j] + ub);
    }
  }
}

// ---------------- persistent cooperative recurrence ----------------
// 64 wgs x 512 threads (8 waves).  wg owns 32 W-rows (output cols), held
// swizzled in 128 KB dynamic LDS.  h kept in registers (acc layout).
// waves: 4 (M batch blocks of 16) x 2 (N col blocks of 16).
__global__ __launch_bounds__(512) void rnn_kernel(
    const f16*   __restrict__ Wf,    // W16 [2048,2048]
    const f16*   __restrict__ Z,     // [512*64,2048]
    const float* __restrict__ OhX,   // [2048]
    const float* __restrict__ ap,    // alpha_param [2048]
    f16*         __restrict__ hbuf,  // [2][64*2048] (tanh(h) comms, f16)
    float*       __restrict__ out)   // out [512*64*2048] then h_final [64*2048]
{
  extern __shared__ char smem[];     // Ws: [32][2048] f16, XOR-swizzled rows
  const int wid = blockIdx.x;        // 0..63
  const int tid = threadIdx.x, lane = tid & 63, w = tid >> 6;
  const int wm = w >> 1, wn = w & 1;
  const int fr = lane & 15, fq = lane >> 4;
  const int r0 = wm * 16;                 // batch row base
  const int col_s = wn * 16 + fr;         // 0..31 within slice
  const int col_g = wid * 32 + col_s;     // global hidden index

  // ---- stage W slice into LDS once (swizzle: byte ^= (row&7)<<4) ----
  for (int i = 0; i < 16; ++i) {
    const int m = tid + i * 512;          // 8192 16B chunks
    const int c = m >> 8;                 // slice row (4096 B/row)
    const int kb = (m & 255) * 16;        // byte offset within row
    f16x8 v = *(const f16x8*)(Wf + (long)(wid * 32 + c) * NH + (kb >> 1));
    *(f16x8*)(smem + c * 4096 + (kb ^ ((c & 7) << 4))) = v;
  }
  // ---- init hbuf[0] slice: tanh(h0), h0 = Oh_X broadcast ----
  for (int idx = tid; idx < 64 * 32; idx += 512) {
    const int b = idx >> 5, c = idx & 31;
    hbuf[b * NH + wid * 32 + c] = (f16)tanhf(OhX[wid * 32 + c]);
  }
  const float alpha = 1.0f / (1.0f + expf(-ap[col_g]));
  float h[4];
#pragma unroll
  for (int j = 0; j < 4; ++j) h[j] = OhX[col_g];
  const int swz = (col_s & 7) << 4;
  const long wsbase = (long)col_s * 4096;
  __syncthreads();

  cooperative_groups::grid_group grid = cooperative_groups::this_grid();
  __threadfence();
  grid.sync();
  __threadfence();

  for (int t = 0; t < T_STEPS; ++t) {
    const f16* hc = hbuf + (t & 1) * (B_SZ * NH);
    f16*       hn = hbuf + ((t + 1) & 1) * (B_SZ * NH);
    f32x4 acc0 = {0.f, 0.f, 0.f, 0.f}, acc1 = {0.f, 0.f, 0.f, 0.f};
    const f16* arow = hc + (r0 + fr) * NH + fq * 8;
#pragma unroll 8
    for (int kk = 0; kk < 64; kk += 2) {
      f16x8 a0 = *(const f16x8*)(arow + kk * 32);
      f16x8 b0 = *(const f16x8*)(smem + wsbase + ((kk * 64 + fq * 16) ^ swz));
      acc0 = __builtin_amdgcn_mfma_f32_16x16x32_f16(a0, b0, acc0, 0, 0, 0);
      f16x8 a1 = *(const f16x8*)(arow + kk * 32 + 32);
      f16x8 b1 = *(const f16x8*)(smem + wsbase + (((kk + 1) * 64 + fq * 16) ^ swz));
      acc1 = __builtin_amdgcn_mfma_f32_16x16x32_f16(a1, b1, acc1, 0, 0, 0);
    }
    const f16* zrow = Z + (long)t * (B_SZ * NH) + (long)(r0 + fq * 4) * NH + col_g;
    float*     orow = out + (long)t * (B_SZ * NH) + (long)(r0 + fq * 4) * NH + col_g;
    f16*       hrow = hn + (r0 + fq * 4) * NH + col_g;
#pragma unroll
    for (int j = 0; j < 4; ++j) {
      const float zv = (float)zrow[j * NH];
      const float hv = alpha * h[j] + zv + (acc0[j] + acc1[j]);
      h[j] = hv;
      const float th = tanhf(hv);
      __builtin_nontemporal_store(th, orow + j * NH);  // write-once stream
      hrow[j * NH] = (f16)th;                          // comms for next step
    }
    __threadfence();   // release: hn visible device-wide (wbL2)
    grid.sync();
    __threadfence();   // acquire: invalidate L1/L2 before reading new hc
  }
  // h_final (raw h after last update)
#pragma unroll
  for (int j = 0; j < 4; ++j)
    out[(long)T_STEPS * B_SZ * NH + (long)(r0 + fq * 4 + j) * NH + col_g] = h[j];
}

extern "C" void kernel_launch(void* const* d_in, const int* in_sizes, int n_in,
                              void* d_out, int out_size, void* d_ws, size_t ws_size,
                              hipStream_t stream) {
  const float* x   = (const float*)d_in[0];   // [512,64,1024]
  const float* U_w = (const float*)d_in[1];   // [2048,1024]
  const float* U_b = (const float*)d_in[2];   // [2048]
  const float* W_w = (const float*)d_in[3];   // [2048,2048]
  const float* OhX = (const float*)d_in[4];   // [1,2048]
  const float* ap  = (const float*)d_in[5];   // [2048]
  char* ws = (char*)d_ws;
  f16*   Z    = (f16*)(ws + WS_Z);
  f16*   hbuf = (f16*)(ws + WS_HBUF);
  f16*   U16  = (f16*)(ws + WS_U16);
  f16*   W16  = (f16*)(ws + WS_W16);
  float* out  = (float*)d_out;

  hipLaunchKernelGGL(cast_uw_kernel, dim3(1024), dim3(256), 0, stream,
                     U_w, W_w, U16, W16);
  hipLaunchKernelGGL(zgemm_kernel, dim3(4096), dim3(256), 0, stream,
                     x, U16, U_b, Z);

  hipFuncSetAttribute((const void*)rnn_kernel,
                      hipFuncAttributeMaxDynamicSharedMemorySize, 131072);
  void* args[] = { (void*)&W16, (void*)&Z, (void*)&OhX, (void*)&ap,
                   (void*)&hbuf, (void*)&out };
  hipLaunchCooperativeKernel((void*)rnn_kernel, dim3(64), dim3(512),
                             args, 131072, stream);
}